// Round 6
// baseline (27.867 us; speedup 1.0000x reference)
//
#include <hip/hip_runtime.h>
#include <hip/hip_bf16.h>

#define NNODE 25
#define HID   128
#define GB    64
#define BLOCK 1024
#define KTOT  256
#define SPAD  264
#define XTW   40     // Xtb row stride (u16): 80B -> 16B-aligned rows, 2-way banks

// ws layout (bytes)
#define WS_WT   0        // u16 [128][256]  W2cat^T bf16 (W2r part pre-scaled by 1/25)
#define WS_MTB  65536    // u16 [32][32]    M bf16, zero-padded
#define WS_CVEC 67584    // f32 [32]        (1/25) * colsum(M), zero-padded
#define WS_W1B  67712    // u16 [128][8]    {W1l[0..2][c], W1r[0..2][c], 0, 0}

typedef __attribute__((ext_vector_type(8))) short short8;
typedef __attribute__((ext_vector_type(4))) float f32x4;
typedef __attribute__((ext_vector_type(2))) float f32x2;

__device__ inline unsigned short f2bf(float f) {
  __hip_bfloat16 h = __float2bfloat16(f);
  unsigned short u; __builtin_memcpy(&u, &h, 2); return u;
}

// Xbf cell: node n (0..24), batch g (0..63); 8 bf16/cell; low-4 bits of g XOR-swizzled
#define XB(n, g) (((n)*GB + ((g) ^ ((n) & 15))) * 8)

__global__ __launch_bounds__(256) void prep(
    const float* __restrict__ W2l, const float* __restrict__ W2r,
    const float* __restrict__ W1l, const float* __restrict__ W1r,
    const int*   __restrict__ ei,  unsigned char* __restrict__ ws)
{
  const int blk = blockIdx.x, tid = threadIdx.x;
  if (blk < 128) {             // Wt[o][k] = bf16(W2cat[k][o]); 1/25 folded into W2r half
    unsigned short* Wt = (unsigned short*)(ws + WS_WT);
    int i = blk*256 + tid;
    int o = i >> 8, k = i & 255;
    float v = (k < HID) ? W2l[k*HID + o] : W2r[(k-HID)*HID + o] * (1.f/NNODE);
    Wt[o*KTOT + k] = f2bf(v);
    return;
  }
  // block 128: M, cvec, W1b
  __shared__ float Mm[NNODE*NNODE];
  __shared__ float cnt[NNODE];
  for (int i = tid; i < NNODE*NNODE; i += 256) Mm[i] = 0.f;
  if (tid < NNODE) cnt[tid] = 0.f;
  __syncthreads();
  if (tid < 64) {
    int s = ei[tid], d = ei[64 + tid];
    atomicAdd(&Mm[d*NNODE + s], 1.f);
    atomicAdd(&cnt[d], 1.f);
  }
  __syncthreads();
  for (int i = tid; i < NNODE*NNODE; i += 256) {
    int n = i / NNODE;
    Mm[i] *= 1.f / fmaxf(cnt[n], 1.f);
  }
  __syncthreads();
  unsigned short* Mtb = (unsigned short*)(ws + WS_MTB);
  for (int i = tid; i < 1024; i += 256) {
    int n = i >> 5, m = i & 31;
    float v = (n < NNODE && m < NNODE) ? Mm[n*NNODE + m] : 0.f;
    Mtb[i] = f2bf(v);
  }
  if (tid < 32) {
    float a = 0.f;
    if (tid < NNODE)
      for (int n = 0; n < NNODE; ++n) a += Mm[n*NNODE + tid];
    ((float*)(ws + WS_CVEC))[tid] = a * (1.f/NNODE);
  }
  unsigned short* W1b = (unsigned short*)(ws + WS_W1B);
  for (int i = tid; i < 1024; i += 256) {
    int c = i >> 3, j = i & 7;
    float v = (j < 3) ? W1l[j*HID + c] : (j < 6) ? W1r[(j-3)*HID + c] : 0.f;
    W1b[i] = f2bf(v);
  }
}

__global__ __launch_bounds__(BLOCK) void gnn_fused(
    const float* __restrict__ x,        // [B][25][3]
    const float* __restrict__ b1,       // [128]
    const float* __restrict__ b2,       // [128]
    const unsigned char* __restrict__ ws,
    float* __restrict__ out)            // [B][128]
{
  __shared__ __align__(16) unsigned short Mtb[32][32];
  __shared__ float cvecs[32];
  __shared__ __align__(16) unsigned short Xtb[3][GB][XTW];  // bf16 x[d][g][m]
  __shared__ __align__(16) unsigned short Xbf[NNODE*GB*8];  // {agg0..2, x0..2, 0, 0}
  __shared__ __align__(16) unsigned short Sbf[GB][SPAD];    // [s1(128) | s2*25(128)]

  const int tid  = threadIdx.x;
  const int b0   = blockIdx.x * GB;
  const int wave = tid >> 6;
  const int lane = tid & 63;
  const int r    = lane & 15;
  const int kg   = lane >> 4;
  const f32x4 zz = {0.f, 0.f, 0.f, 0.f};

  // ---- phase A: issue x loads (float4), tables, pad-zeroing (disjoint), scatter ----
  f32x4 xv[2];
  int   i4v[2];
  #pragma unroll
  for (int t = 0; t < 2; ++t) {
    int i4 = tid + t*BLOCK;
    i4v[t] = i4;
    if (i4 < GB*75/4) xv[t] = ((const f32x4*)(x + (size_t)b0*75))[i4];
  }
  if (tid < 512)
    ((unsigned int*)Mtb)[tid] = ((const unsigned int*)(ws + WS_MTB))[tid];
  if (tid < 32) cvecs[tid] = ((const float*)(ws + WS_CVEC))[tid];
  // zero ONLY the pad tail m in [25,32) — disjoint from the x-scatter (m<25)
  for (int i = tid; i < 3*GB*7; i += BLOCK) {
    int d = i / (GB*7), rm = i % (GB*7);
    Xtb[d][rm/7][25 + rm%7] = 0;
  }
  for (int p = tid; p < NNODE*GB; p += BLOCK)              // Xbf slots 6,7 = 0
    *(unsigned int*)&Xbf[XB(p >> 6, p & 63) + 6] = 0u;
  #pragma unroll
  for (int t = 0; t < 2; ++t) {
    if (i4v[t] < GB*75/4) {
      #pragma unroll
      for (int j = 0; j < 4; ++j) {
        int e = i4v[t]*4 + j;
        int g = e / 75, rm = e - g*75;
        int n = rm / 3, d = rm - n*3;
        unsigned short bv = f2bf(xv[t][j]);
        Xtb[d][g][n] = bv;
        Xbf[XB(n, g) + 3 + d] = bv;
      }
    }
  }
  __syncthreads();

  // ---- phase B: agg via MFMA; waves 0..11 -> (d, g-tile of 16) ----
  if (wave < 12) {
    const int d = wave >> 2, gt = wave & 3;
    short8 mb0 = *(const short8*)&Mtb[r][kg*8];        // B[k=m][col=n], n=r
    short8 mb1 = *(const short8*)&Mtb[16 + r][kg*8];   // n=16+r (rows >=25 zero)
    short8 af  = *(const short8*)&Xtb[d][gt*16 + r][kg*8];  // A[row=g][k=m]
    f32x4 g0 = __builtin_amdgcn_mfma_f32_16x16x32_bf16(af, mb0, zz, 0, 0, 0);
    f32x4 g1 = __builtin_amdgcn_mfma_f32_16x16x32_bf16(af, mb1, zz, 0, 0, 0);
    #pragma unroll
    for (int q = 0; q < 4; ++q) {
      int g = gt*16 + kg*4 + q;          // C row = batch (within block)
      Xbf[XB(r, g) + d] = f2bf(g0[q]);   // C col = node n = r
      if (r < 9) Xbf[XB(16 + r, g) + d] = f2bf(g1[q]);
    }
  }
  __syncthreads();

  // ---- phase C: stage 1 via MFMA (K=8 eff), bias in C, packed-f32 n-reduce ----
  {
    const int gt = wave >> 2;
    const int c0 = (wave & 3) * 32;
    const int cA = c0 + r, cB = c0 + 16 + r;
    const unsigned short* W1b = (const unsigned short*)(ws + WS_W1B);
    short8 bfA = {0,0,0,0,0,0,0,0}, bfB = {0,0,0,0,0,0,0,0};
    if (kg == 0) {
      bfA = *(const short8*)&W1b[cA * 8];
      bfB = *(const short8*)&W1b[cB * 8];
    }
    const float biasA = b1[cA], biasB = b1[cB];
    const f32x4 cbA = {biasA, biasA, biasA, biasA};
    const f32x4 cbB = {biasB, biasB, biasB, biasB};
    f32x2 s1[4] = {}, s2[4] = {};
    #pragma unroll 5
    for (int n = 0; n < NNODE; ++n) {
      short8 a = *(const short8*)&Xbf[XB(n, gt*16 + r)];
      f32x4 h0 = __builtin_amdgcn_mfma_f32_16x16x32_bf16(a, bfA, cbA, 0, 0, 0);
      f32x4 h1 = __builtin_amdgcn_mfma_f32_16x16x32_bf16(a, bfB, cbB, 0, 0, 0);
      const float cv = cvecs[n];
      const f32x2 cvv = {cv, cv};
      #pragma unroll
      for (int q = 0; q < 4; ++q) {
        f32x2 v; v.x = fmaxf(h0[q], 0.f); v.y = fmaxf(h1[q], 0.f);
        s1[q] += cvv * v;
        s2[q] += v;
      }
    }
    #pragma unroll
    for (int q = 0; q < 4; ++q) {
      int g = gt*16 + kg*4 + q;
      Sbf[g][cA]       = f2bf(s1[q].x);
      Sbf[g][cB]       = f2bf(s1[q].y);
      Sbf[g][HID + cA] = f2bf(s2[q].x);   // 1/25 folded into Wt's W2r half
      Sbf[g][HID + cB] = f2bf(s2[q].y);
    }
  }
  __syncthreads();

  // ---- phase D: out[64x128] = S[64x256] @ W2cat via MFMA ----
  {
    const int gt = wave >> 2;
    const int n0 = (wave & 3) * 32;
    const unsigned short* Wt = (const unsigned short*)(ws + WS_WT);
    const unsigned short* WtA = Wt + (size_t)(n0 + r)      * KTOT;
    const unsigned short* WtB = Wt + (size_t)(n0 + 16 + r) * KTOT;
    f32x4 acc0 = zz, acc1 = zz;
    #pragma unroll 4
    for (int kt = 0; kt < 8; ++kt) {
      const int kb = kt*32 + kg*8;
      short8 a  = *(const short8*)&Sbf[gt*16 + r][kb];
      short8 bA = *(const short8*)&WtA[kb];
      short8 bB = *(const short8*)&WtB[kb];
      acc0 = __builtin_amdgcn_mfma_f32_16x16x32_bf16(a, bA, acc0, 0, 0, 0);
      acc1 = __builtin_amdgcn_mfma_f32_16x16x32_bf16(a, bB, acc1, 0, 0, 0);
    }
    const int colA = n0 + r, colB = n0 + 16 + r;
    const float bA2 = b2[colA], bB2 = b2[colB];
    #pragma unroll
    for (int q = 0; q < 4; ++q) {
      const int row = gt*16 + kg*4 + q;
      out[(size_t)(b0+row)*HID + colA] = acc0[q] + bA2;
      out[(size_t)(b0+row)*HID + colB] = acc1[q] + bB2;
    }
  }
}

extern "C" void kernel_launch(void* const* d_in, const int* in_sizes, int n_in,
                              void* d_out, int out_size, void* d_ws, size_t ws_size,
                              hipStream_t stream) {
  (void)n_in; (void)out_size; (void)ws_size;
  const float* x   = (const float*)d_in[0];
  const int*   ei  = (const int*)  d_in[1];
  const float* W1l = (const float*)d_in[2];
  const float* W1r = (const float*)d_in[3];
  const float* b1  = (const float*)d_in[4];
  const float* W2l = (const float*)d_in[5];
  const float* W2r = (const float*)d_in[6];
  const float* b2  = (const float*)d_in[7];
  float* out = (float*)d_out;
  unsigned char* ws = (unsigned char*)d_ws;

  const int B = in_sizes[0] / (NNODE*3);   // 16384
  prep<<<dim3(129), dim3(256), 0, stream>>>(W2l, W2r, W1l, W1r, ei, ws);
  gnn_fused<<<dim3(B / GB), dim3(BLOCK), 0, stream>>>(x, b1, b2, ws, out);
}

// Round 7
// 25.089 us; speedup vs baseline: 1.1107x; 1.1107x over previous
//
#include <hip/hip_runtime.h>
#include <hip/hip_bf16.h>

#define NNODE 25
#define HID   128
#define GB    32
#define BLOCK 512
#define KTOT  256
#define SPAD  264
#define XTW   40     // Xtb row stride (u16): 80B -> 16B-aligned rows, 2-way banks

// ws layout (bytes)
#define WS_WT   0        // u16 [128][256]  W2cat^T bf16 (W2r part pre-scaled by 1/25)
#define WS_MTB  65536    // u16 [32][32]    M bf16, zero-padded
#define WS_CVEC 67584    // f32 [32]        (1/25) * colsum(M), zero-padded
#define WS_W1B  67712    // u16 [128][8]    {W1l[0..2][c], W1r[0..2][c], 0, 0}

typedef __attribute__((ext_vector_type(8))) short short8;
typedef __attribute__((ext_vector_type(4))) float f32x4;
typedef __attribute__((ext_vector_type(2))) float f32x2;

__device__ inline unsigned short f2bf(float f) {
  __hip_bfloat16 h = __float2bfloat16(f);
  unsigned short u; __builtin_memcpy(&u, &h, 2); return u;
}

// Xbf cell: node n (0..24), batch g (0..31); 8 bf16/cell; low-4 bits of g XOR-swizzled
#define XB(n, g) (((n)*GB + ((g) ^ ((n) & 15))) * 8)

__global__ __launch_bounds__(256) void prep(
    const float* __restrict__ W2l, const float* __restrict__ W2r,
    const float* __restrict__ W1l, const float* __restrict__ W1r,
    const int*   __restrict__ ei,  unsigned char* __restrict__ ws)
{
  const int blk = blockIdx.x, tid = threadIdx.x;
  if (blk < 128) {             // Wt[o][k] = bf16(W2cat[k][o]); 1/25 folded into W2r half
    unsigned short* Wt = (unsigned short*)(ws + WS_WT);
    int i = blk*256 + tid;
    int o = i >> 8, k = i & 255;
    float v = (k < HID) ? W2l[k*HID + o] : W2r[(k-HID)*HID + o] * (1.f/NNODE);
    Wt[o*KTOT + k] = f2bf(v);
    return;
  }
  // block 128: M, cvec, W1b
  __shared__ float Mm[NNODE*NNODE];
  __shared__ float cnt[NNODE];
  for (int i = tid; i < NNODE*NNODE; i += 256) Mm[i] = 0.f;
  if (tid < NNODE) cnt[tid] = 0.f;
  __syncthreads();
  if (tid < 64) {
    int s = ei[tid], d = ei[64 + tid];
    atomicAdd(&Mm[d*NNODE + s], 1.f);
    atomicAdd(&cnt[d], 1.f);
  }
  __syncthreads();
  for (int i = tid; i < NNODE*NNODE; i += 256) {
    int n = i / NNODE;
    Mm[i] *= 1.f / fmaxf(cnt[n], 1.f);
  }
  __syncthreads();
  unsigned short* Mtb = (unsigned short*)(ws + WS_MTB);
  for (int i = tid; i < 1024; i += 256) {
    int n = i >> 5, m = i & 31;
    float v = (n < NNODE && m < NNODE) ? Mm[n*NNODE + m] : 0.f;
    Mtb[i] = f2bf(v);
  }
  if (tid < 32) {
    float a = 0.f;
    if (tid < NNODE)
      for (int n = 0; n < NNODE; ++n) a += Mm[n*NNODE + tid];
    ((float*)(ws + WS_CVEC))[tid] = a * (1.f/NNODE);
  }
  unsigned short* W1b = (unsigned short*)(ws + WS_W1B);
  for (int i = tid; i < 1024; i += 256) {
    int c = i >> 3, j = i & 7;
    float v = (j < 3) ? W1l[j*HID + c] : (j < 6) ? W1r[(j-3)*HID + c] : 0.f;
    W1b[i] = f2bf(v);
  }
}

__global__ __launch_bounds__(BLOCK, 4) void gnn_fused(
    const float* __restrict__ x,        // [B][25][3]
    const float* __restrict__ b1,       // [128]
    const float* __restrict__ b2,       // [128]
    const unsigned char* __restrict__ ws,
    float* __restrict__ out)            // [B][128]
{
  __shared__ __align__(16) unsigned short Mtb[32][32];
  __shared__ float cvecs[32];
  __shared__ __align__(16) unsigned short Xtb[3][GB][XTW];  // bf16 x[d][g][m]
  __shared__ __align__(16) unsigned short Xbf[NNODE*GB*8];  // {agg0..2, x0..2, 0, 0}
  __shared__ __align__(16) unsigned short Sbf[GB][SPAD];    // [s1(128) | s2*25(128)]

  const int tid  = threadIdx.x;
  const int b0   = blockIdx.x * GB;
  const int wave = tid >> 6;
  const int lane = tid & 63;
  const int r    = lane & 15;
  const int kg   = lane >> 4;
  const f32x4 zz = {0.f, 0.f, 0.f, 0.f};

  // ---- phase A: issue x loads (float4), tables, pad-zeroing (disjoint), scatter ----
  f32x4 xv[2];
  int   i4v[2];
  #pragma unroll
  for (int t = 0; t < 2; ++t) {
    int i4 = tid + t*BLOCK;
    i4v[t] = i4;
    if (i4 < GB*75/4) xv[t] = ((const f32x4*)(x + (size_t)b0*75))[i4];
  }
  ((unsigned int*)Mtb)[tid] = ((const unsigned int*)(ws + WS_MTB))[tid];
  if (tid < 32) cvecs[tid] = ((const float*)(ws + WS_CVEC))[tid];
  // zero ONLY the pad tail m in [25,32) of Xtb — disjoint from the x-scatter (m<25)
  for (int i = tid; i < 3*GB*7; i += BLOCK) {
    int d = i / (GB*7), rm = i % (GB*7);
    Xtb[d][rm/7][25 + rm%7] = 0;
  }
  for (int p = tid; p < NNODE*GB; p += BLOCK)              // Xbf slots 6,7 = 0
    *(unsigned int*)&Xbf[XB(p >> 5, p & 31) + 6] = 0u;
  #pragma unroll
  for (int t = 0; t < 2; ++t) {
    if (i4v[t] < GB*75/4) {
      #pragma unroll
      for (int j = 0; j < 4; ++j) {
        int e = i4v[t]*4 + j;
        int g = e / 75, rm = e - g*75;
        int n = rm / 3, d = rm - n*3;
        unsigned short bv = f2bf(xv[t][j]);
        Xtb[d][g][n] = bv;
        Xbf[XB(n, g) + 3 + d] = bv;
      }
    }
  }
  __syncthreads();

  // ---- phase B: agg via MFMA; waves 0..5 -> (d, g-tile of 16) ----
  if (wave < 6) {
    const int d = wave >> 1, gt = wave & 1;
    short8 mb0 = *(const short8*)&Mtb[r][kg*8];        // B[k=m][col=n], n=r
    short8 mb1 = *(const short8*)&Mtb[16 + r][kg*8];   // n=16+r (rows >=25 zero)
    short8 af  = *(const short8*)&Xtb[d][gt*16 + r][kg*8];  // A[row=g][k=m]
    f32x4 g0 = __builtin_amdgcn_mfma_f32_16x16x32_bf16(af, mb0, zz, 0, 0, 0);
    f32x4 g1 = __builtin_amdgcn_mfma_f32_16x16x32_bf16(af, mb1, zz, 0, 0, 0);
    #pragma unroll
    for (int q = 0; q < 4; ++q) {
      int g = gt*16 + kg*4 + q;          // C row = batch (within block)
      Xbf[XB(r, g) + d] = f2bf(g0[q]);   // C col = node n = r
      if (r < 9) Xbf[XB(16 + r, g) + d] = f2bf(g1[q]);
    }
  }
  __syncthreads();

  // ---- phase C: stage 1 via MFMA, 2 nodes per iteration (K slots 0,1) ----
  {
    const int gt = wave >> 2;            // batch half
    const int c0 = (wave & 3) * 32;
    const int cA = c0 + r, cB = c0 + 16 + r;
    const unsigned short* W1b = (const unsigned short*)(ws + WS_W1B);
    const short8 w1A = *(const short8*)&W1b[cA * 8];
    const short8 w1B = *(const short8*)&W1b[cB * 8];
    const short8 z8  = {0,0,0,0,0,0,0,0};
    // slot-masked B fragments: slot0 -> B rows 0..7, slot1 -> B rows 8..15
    const short8 bA0 = (kg == 0) ? w1A : z8;
    const short8 bA1 = (kg == 1) ? w1A : z8;
    const short8 bB0 = (kg == 0) ? w1B : z8;
    const short8 bB1 = (kg == 1) ? w1B : z8;
    const float biasA = b1[cA], biasB = b1[cB];
    const f32x4 cbA = {biasA, biasA, biasA, biasA};
    const f32x4 cbB = {biasB, biasB, biasB, biasB};
    f32x2 s1[4] = {}, s2[4] = {};
    for (int ng = 0; ng < 12; ++ng) {    // nodes 2ng (slot0), 2ng+1 (slot1)
      // lanes kg=0/2 read node 2ng, kg=1/3 read node 2ng+1 (slices k>=16 hit zero B)
      short8 a = *(const short8*)&Xbf[XB(2*ng + (kg & 1), gt*16 + r)];
      f32x4 h0e = __builtin_amdgcn_mfma_f32_16x16x32_bf16(a, bA0, cbA, 0, 0, 0);
      f32x4 h1e = __builtin_amdgcn_mfma_f32_16x16x32_bf16(a, bB0, cbB, 0, 0, 0);
      f32x4 h0o = __builtin_amdgcn_mfma_f32_16x16x32_bf16(a, bA1, cbA, 0, 0, 0);
      f32x4 h1o = __builtin_amdgcn_mfma_f32_16x16x32_bf16(a, bB1, cbB, 0, 0, 0);
      const float cv0 = cvecs[2*ng], cv1 = cvecs[2*ng + 1];
      const f32x2 cvv0 = {cv0, cv0}, cvv1 = {cv1, cv1};
      #pragma unroll
      for (int q = 0; q < 4; ++q) {
        f32x2 ve; ve.x = fmaxf(h0e[q], 0.f); ve.y = fmaxf(h1e[q], 0.f);
        f32x2 vo; vo.x = fmaxf(h0o[q], 0.f); vo.y = fmaxf(h1o[q], 0.f);
        s1[q] += cvv0 * ve; s2[q] += ve;
        s1[q] += cvv1 * vo; s2[q] += vo;
      }
    }
    {  // epilogue: node 24 via slot 0 only
      short8 a = *(const short8*)&Xbf[XB(24, gt*16 + r)];
      f32x4 h0 = __builtin_amdgcn_mfma_f32_16x16x32_bf16(a, bA0, cbA, 0, 0, 0);
      f32x4 h1 = __builtin_amdgcn_mfma_f32_16x16x32_bf16(a, bB0, cbB, 0, 0, 0);
      const float cv = cvecs[24];
      const f32x2 cvv = {cv, cv};
      #pragma unroll
      for (int q = 0; q < 4; ++q) {
        f32x2 v; v.x = fmaxf(h0[q], 0.f); v.y = fmaxf(h1[q], 0.f);
        s1[q] += cvv * v;
        s2[q] += v;
      }
    }
    #pragma unroll
    for (int q = 0; q < 4; ++q) {
      int g = gt*16 + kg*4 + q;
      Sbf[g][cA]       = f2bf(s1[q].x);
      Sbf[g][cB]       = f2bf(s1[q].y);
      Sbf[g][HID + cA] = f2bf(s2[q].x);   // 1/25 folded into Wt's W2r half
      Sbf[g][HID + cB] = f2bf(s2[q].y);
    }
  }
  __syncthreads();

  // ---- phase D: out[32x128] = S[32x256] @ W2cat via MFMA ----
  {
    const int gt = wave >> 2;
    const int n0 = (wave & 3) * 32;
    const unsigned short* Wt = (const unsigned short*)(ws + WS_WT);
    const unsigned short* WtA = Wt + (size_t)(n0 + r)      * KTOT;
    const unsigned short* WtB = Wt + (size_t)(n0 + 16 + r) * KTOT;
    f32x4 acc0 = zz, acc1 = zz;
    #pragma unroll 4
    for (int kt = 0; kt < 8; ++kt) {
      const int kb = kt*32 + kg*8;
      short8 a  = *(const short8*)&Sbf[gt*16 + r][kb];
      short8 bA = *(const short8*)&WtA[kb];
      short8 bB = *(const short8*)&WtB[kb];
      acc0 = __builtin_amdgcn_mfma_f32_16x16x32_bf16(a, bA, acc0, 0, 0, 0);
      acc1 = __builtin_amdgcn_mfma_f32_16x16x32_bf16(a, bB, acc1, 0, 0, 0);
    }
    const int colA = n0 + r, colB = n0 + 16 + r;
    const float bA2 = b2[colA], bB2 = b2[colB];
    #pragma unroll
    for (int q = 0; q < 4; ++q) {
      const int row = gt*16 + kg*4 + q;
      out[(size_t)(b0+row)*HID + colA] = acc0[q] + bA2;
      out[(size_t)(b0+row)*HID + colB] = acc1[q] + bB2;
    }
  }
}

extern "C" void kernel_launch(void* const* d_in, const int* in_sizes, int n_in,
                              void* d_out, int out_size, void* d_ws, size_t ws_size,
                              hipStream_t stream) {
  (void)n_in; (void)out_size; (void)ws_size;
  const float* x   = (const float*)d_in[0];
  const int*   ei  = (const int*)  d_in[1];
  const float* W1l = (const float*)d_in[2];
  const float* W1r = (const float*)d_in[3];
  const float* b1  = (const float*)d_in[4];
  const float* W2l = (const float*)d_in[5];
  const float* W2r = (const float*)d_in[6];
  const float* b2  = (const float*)d_in[7];
  float* out = (float*)d_out;
  unsigned char* ws = (unsigned char*)d_ws;

  const int B = in_sizes[0] / (NNODE*3);   // 16384
  prep<<<dim3(129), dim3(256), 0, stream>>>(W2l, W2r, W1l, W1r, ei, ws);
  gnn_fused<<<dim3(B / GB), dim3(BLOCK), 0, stream>>>(x, b1, b2, ws, out);
}

// Round 8
// 23.793 us; speedup vs baseline: 1.1712x; 1.0545x over previous
//
#include <hip/hip_runtime.h>
#include <hip/hip_bf16.h>

#define NNODE 25
#define HID   128
#define GB    16
#define BLOCK 256
#define KTOT  256
#define SPAD  264
#define XTW   40     // Xtb row stride (u16): 80B -> 16B-aligned rows, 2-way banks

// ws layout (bytes)
#define WS_WT   0        // u16 [128][256]  W2cat^T bf16 (W2r part pre-scaled by 1/25)
#define WS_MTB  65536    // u16 [32][32]    M bf16, zero-padded
#define WS_CVEC 67584    // f32 [32]        (1/25) * colsum(M), zero-padded
#define WS_W1B  67712    // u16 [128][8]    {W1l[0..2][c], W1r[0..2][c], 0, 0}

typedef __attribute__((ext_vector_type(8))) short short8;
typedef __attribute__((ext_vector_type(4))) float f32x4;
typedef __attribute__((ext_vector_type(2))) float f32x2;

__device__ inline unsigned short f2bf(float f) {
  __hip_bfloat16 h = __float2bfloat16(f);
  unsigned short u; __builtin_memcpy(&u, &h, 2); return u;
}

// Xbf cell: node n (0..24), batch g (0..15); 8 bf16/cell; g XOR-swizzled
#define XB(n, g) (((n)*GB + ((g) ^ ((n) & 15))) * 8)

__global__ __launch_bounds__(256) void prep(
    const float* __restrict__ W2l, const float* __restrict__ W2r,
    const float* __restrict__ W1l, const float* __restrict__ W1r,
    const int*   __restrict__ ei,  unsigned char* __restrict__ ws)
{
  const int blk = blockIdx.x, tid = threadIdx.x;
  if (blk < 128) {             // Wt[o][k] = bf16(W2cat[k][o]); 1/25 folded into W2r half
    unsigned short* Wt = (unsigned short*)(ws + WS_WT);
    int i = blk*256 + tid;
    int o = i >> 8, k = i & 255;
    float v = (k < HID) ? W2l[k*HID + o] : W2r[(k-HID)*HID + o] * (1.f/NNODE);
    Wt[o*KTOT + k] = f2bf(v);
    return;
  }
  // block 128: M, cvec, W1b
  __shared__ float Mm[NNODE*NNODE];
  __shared__ float cnt[NNODE];
  for (int i = tid; i < NNODE*NNODE; i += 256) Mm[i] = 0.f;
  if (tid < NNODE) cnt[tid] = 0.f;
  __syncthreads();
  if (tid < 64) {
    int s = ei[tid], d = ei[64 + tid];
    atomicAdd(&Mm[d*NNODE + s], 1.f);
    atomicAdd(&cnt[d], 1.f);
  }
  __syncthreads();
  for (int i = tid; i < NNODE*NNODE; i += 256) {
    int n = i / NNODE;
    Mm[i] *= 1.f / fmaxf(cnt[n], 1.f);
  }
  __syncthreads();
  unsigned short* Mtb = (unsigned short*)(ws + WS_MTB);
  for (int i = tid; i < 1024; i += 256) {
    int n = i >> 5, m = i & 31;
    float v = (n < NNODE && m < NNODE) ? Mm[n*NNODE + m] : 0.f;
    Mtb[i] = f2bf(v);
  }
  if (tid < 32) {
    float a = 0.f;
    if (tid < NNODE)
      for (int n = 0; n < NNODE; ++n) a += Mm[n*NNODE + tid];
    ((float*)(ws + WS_CVEC))[tid] = a * (1.f/NNODE);
  }
  unsigned short* W1b = (unsigned short*)(ws + WS_W1B);
  for (int i = tid; i < 1024; i += 256) {
    int c = i >> 3, j = i & 7;
    float v = (j < 3) ? W1l[j*HID + c] : (j < 6) ? W1r[(j-3)*HID + c] : 0.f;
    W1b[i] = f2bf(v);
  }
}

__global__ __launch_bounds__(BLOCK, 5) void gnn_fused(
    const float* __restrict__ x,        // [B][25][3]
    const float* __restrict__ b1,       // [128]
    const float* __restrict__ b2,       // [128]
    const unsigned char* __restrict__ ws,
    float* __restrict__ out)            // [B][128]
{
  __shared__ __align__(16) unsigned short Mtb[32][32];
  __shared__ float cvecs[32];
  __shared__ __align__(16) unsigned short Xtb[3][GB][XTW];  // bf16 x[d][g][m]
  __shared__ __align__(16) unsigned short Xbf[NNODE*GB*8];  // {agg0..2, x0..2, 0, 0}
  __shared__ __align__(16) unsigned short Sbf[GB][SPAD];    // [s1(128) | s2*25(128)]

  const int tid  = threadIdx.x;
  const int b0   = blockIdx.x * GB;
  const int wave = tid >> 6;
  const int lane = tid & 63;
  const int r    = lane & 15;
  const int kg   = lane >> 4;
  const f32x4 zz = {0.f, 0.f, 0.f, 0.f};

  // ---- phase A: issue x loads (float4), tables, pad-zeroing (disjoint), scatter ----
  f32x4 xv[2];
  int   i4v[2];
  #pragma unroll
  for (int t = 0; t < 2; ++t) {
    int i4 = tid + t*BLOCK;
    i4v[t] = i4;
    if (i4 < GB*75/4) xv[t] = ((const f32x4*)(x + (size_t)b0*75))[i4];
  }
  for (int i = tid; i < 512; i += BLOCK)
    ((unsigned int*)Mtb)[i] = ((const unsigned int*)(ws + WS_MTB))[i];
  if (tid < 32) cvecs[tid] = ((const float*)(ws + WS_CVEC))[tid];
  // zero ONLY the pad tail m in [25,32) of Xtb — disjoint from the x-scatter (m<25)
  for (int i = tid; i < 3*GB*7; i += BLOCK) {
    int d = i / (GB*7), rm = i % (GB*7);
    Xtb[d][rm/7][25 + rm%7] = 0;
  }
  for (int p = tid; p < NNODE*GB; p += BLOCK)              // Xbf slots 6,7 = 0
    *(unsigned int*)&Xbf[XB(p >> 4, p & 15) + 6] = 0u;
  #pragma unroll
  for (int t = 0; t < 2; ++t) {
    if (i4v[t] < GB*75/4) {
      #pragma unroll
      for (int j = 0; j < 4; ++j) {
        int e = i4v[t]*4 + j;
        int g = e / 75, rm = e - g*75;
        int n = rm / 3, d = rm - n*3;
        unsigned short bv = f2bf(xv[t][j]);
        Xtb[d][g][n] = bv;
        Xbf[XB(n, g) + 3 + d] = bv;
      }
    }
  }
  __syncthreads();

  // ---- phase B: agg via MFMA; waves 0..2 -> one d each ----
  if (wave < 3) {
    const int d = wave;
    short8 mb0 = *(const short8*)&Mtb[r][kg*8];        // B[k=m][col=n], n=r
    short8 mb1 = *(const short8*)&Mtb[16 + r][kg*8];   // n=16+r (rows >=25 zero)
    short8 af  = *(const short8*)&Xtb[d][r][kg*8];     // A[row=g][k=m]
    f32x4 g0 = __builtin_amdgcn_mfma_f32_16x16x32_bf16(af, mb0, zz, 0, 0, 0);
    f32x4 g1 = __builtin_amdgcn_mfma_f32_16x16x32_bf16(af, mb1, zz, 0, 0, 0);
    #pragma unroll
    for (int q = 0; q < 4; ++q) {
      int g = kg*4 + q;                  // C row = batch (within block)
      Xbf[XB(r, g) + d] = f2bf(g0[q]);   // C col = node n = r
      if (r < 9) Xbf[XB(16 + r, g) + d] = f2bf(g1[q]);
    }
  }
  __syncthreads();

  // ---- phase C: stage 1 via MFMA, 2 nodes per iteration (K slots 0,1) ----
  {
    const int c0 = wave * 32;
    const int cA = c0 + r, cB = c0 + 16 + r;
    const unsigned short* W1b = (const unsigned short*)(ws + WS_W1B);
    const short8 w1A = *(const short8*)&W1b[cA * 8];
    const short8 w1B = *(const short8*)&W1b[cB * 8];
    const short8 z8  = {0,0,0,0,0,0,0,0};
    // slot-masked B fragments: slot0 -> B rows 0..7, slot1 -> B rows 8..15
    const short8 bA0 = (kg == 0) ? w1A : z8;
    const short8 bA1 = (kg == 1) ? w1A : z8;
    const short8 bB0 = (kg == 0) ? w1B : z8;
    const short8 bB1 = (kg == 1) ? w1B : z8;
    const float biasA = b1[cA], biasB = b1[cB];
    const f32x4 cbA = {biasA, biasA, biasA, biasA};
    const f32x4 cbB = {biasB, biasB, biasB, biasB};
    f32x2 s1[4] = {}, s2[4] = {};
    for (int ng = 0; ng < 12; ++ng) {    // nodes 2ng (slot0), 2ng+1 (slot1)
      short8 a = *(const short8*)&Xbf[XB(2*ng + (kg & 1), r)];
      f32x4 h0e = __builtin_amdgcn_mfma_f32_16x16x32_bf16(a, bA0, cbA, 0, 0, 0);
      f32x4 h1e = __builtin_amdgcn_mfma_f32_16x16x32_bf16(a, bB0, cbB, 0, 0, 0);
      f32x4 h0o = __builtin_amdgcn_mfma_f32_16x16x32_bf16(a, bA1, cbA, 0, 0, 0);
      f32x4 h1o = __builtin_amdgcn_mfma_f32_16x16x32_bf16(a, bB1, cbB, 0, 0, 0);
      const float cv0 = cvecs[2*ng], cv1 = cvecs[2*ng + 1];
      const f32x2 cvv0 = {cv0, cv0}, cvv1 = {cv1, cv1};
      #pragma unroll
      for (int q = 0; q < 4; ++q) {
        f32x2 ve; ve.x = fmaxf(h0e[q], 0.f); ve.y = fmaxf(h1e[q], 0.f);
        f32x2 vo; vo.x = fmaxf(h0o[q], 0.f); vo.y = fmaxf(h1o[q], 0.f);
        s1[q] += cvv0 * ve; s2[q] += ve;
        s1[q] += cvv1 * vo; s2[q] += vo;
      }
    }
    {  // epilogue: node 24 via slot 0 only
      short8 a = *(const short8*)&Xbf[XB(24, r)];
      f32x4 h0 = __builtin_amdgcn_mfma_f32_16x16x32_bf16(a, bA0, cbA, 0, 0, 0);
      f32x4 h1 = __builtin_amdgcn_mfma_f32_16x16x32_bf16(a, bB0, cbB, 0, 0, 0);
      const float cv = cvecs[24];
      const f32x2 cvv = {cv, cv};
      #pragma unroll
      for (int q = 0; q < 4; ++q) {
        f32x2 v; v.x = fmaxf(h0[q], 0.f); v.y = fmaxf(h1[q], 0.f);
        s1[q] += cvv * v;
        s2[q] += v;
      }
    }
    #pragma unroll
    for (int q = 0; q < 4; ++q) {
      int g = kg*4 + q;
      Sbf[g][cA]       = f2bf(s1[q].x);
      Sbf[g][cB]       = f2bf(s1[q].y);
      Sbf[g][HID + cA] = f2bf(s2[q].x);   // 1/25 folded into Wt's W2r half
      Sbf[g][HID + cB] = f2bf(s2[q].y);
    }
  }
  __syncthreads();

  // ---- phase D: out[16x128] = S[16x256] @ W2cat via MFMA ----
  {
    const int n0 = wave * 32;
    const unsigned short* Wt = (const unsigned short*)(ws + WS_WT);
    const unsigned short* WtA = Wt + (size_t)(n0 + r)      * KTOT;
    const unsigned short* WtB = Wt + (size_t)(n0 + 16 + r) * KTOT;
    f32x4 acc0 = zz, acc1 = zz;
    #pragma unroll 4
    for (int kt = 0; kt < 8; ++kt) {
      const int kb = kt*32 + kg*8;
      short8 a  = *(const short8*)&Sbf[r][kb];
      short8 bA = *(const short8*)&WtA[kb];
      short8 bB = *(const short8*)&WtB[kb];
      acc0 = __builtin_amdgcn_mfma_f32_16x16x32_bf16(a, bA, acc0, 0, 0, 0);
      acc1 = __builtin_amdgcn_mfma_f32_16x16x32_bf16(a, bB, acc1, 0, 0, 0);
    }
    const int colA = n0 + r, colB = n0 + 16 + r;
    const float bA2 = b2[colA], bB2 = b2[colB];
    #pragma unroll
    for (int q = 0; q < 4; ++q) {
      const int row = kg*4 + q;
      out[(size_t)(b0+row)*HID + colA] = acc0[q] + bA2;
      out[(size_t)(b0+row)*HID + colB] = acc1[q] + bB2;
    }
  }
}

extern "C" void kernel_launch(void* const* d_in, const int* in_sizes, int n_in,
                              void* d_out, int out_size, void* d_ws, size_t ws_size,
                              hipStream_t stream) {
  (void)n_in; (void)out_size; (void)ws_size;
  const float* x   = (const float*)d_in[0];
  const int*   ei  = (const int*)  d_in[1];
  const float* W1l = (const float*)d_in[2];
  const float* W1r = (const float*)d_in[3];
  const float* b1  = (const float*)d_in[4];
  const float* W2l = (const float*)d_in[5];
  const float* W2r = (const float*)d_in[6];
  const float* b2  = (const float*)d_in[7];
  float* out = (float*)d_out;
  unsigned char* ws = (unsigned char*)d_ws;

  const int B = in_sizes[0] / (NNODE*3);   // 16384
  prep<<<dim3(129), dim3(256), 0, stream>>>(W2l, W2r, W1l, W1r, ei, ws);
  gnn_fused<<<dim3(B / GB), dim3(BLOCK), 0, stream>>>(x, b1, b2, ws, out);
}